// Round 14
// baseline (116.571 us; speedup 1.0000x reference)
//
#include <hip/hip_runtime.h>
#include <hip/hip_bf16.h>
#include <cstdio>

#define T_DIM 2048
#define B_DIM 2
#define E_DIM 1024
#define H_DIM 16
#define S_DIM 64
#define LOG2E 1.44269504088896340736f

typedef __attribute__((ext_vector_type(4))) float f32x4;
typedef __attribute__((ext_vector_type(16))) float f32x16;
typedef __attribute__((ext_vector_type(8))) short bf16x8;
typedef __attribute__((ext_vector_type(8))) unsigned short u16x8;
typedef __attribute__((ext_vector_type(4))) unsigned short u16x4;

#define MFMA32(a,b,c) __builtin_amdgcn_mfma_f32_32x32x16_bf16((a),(b),(c),0,0,0)

__device__ __forceinline__ unsigned short f2bf(float f) {
    union { __hip_bfloat16 h; unsigned short u; } c;
    c.h = __float2bfloat16(f);
    return c.u;
}
__device__ __forceinline__ void gload16(const void* g, void* l) {
    __builtin_amdgcn_global_load_lds(
        (const __attribute__((address_space(1))) unsigned int*)g,
        (__attribute__((address_space(3))) unsigned int*)l, 16, 0, 0);
}
__device__ __forceinline__ f32x16 zero16() {
    f32x16 v;
#pragma unroll
    for (int i = 0; i < 16; ++i) v[i] = 0.f;
    return v;
}

// ---------------- Kernel 0: weight prep (all weights -> bf16) ----------------
__global__ __launch_bounds__(256) void prep_w(
    const float* __restrict__ Wq, const float* __restrict__ Wk,
    const float* __restrict__ Wv, const float* __restrict__ Wr,
    unsigned short* __restrict__ whb, unsigned short* __restrict__ wrb)
{
    int bid = blockIdx.x;
    if (bid < 192) {
        int i = bid * 256 + threadIdx.x;   // float4 idx < 49152
        const float* src = (i < 16384) ? Wq : ((i < 32768) ? Wk : Wv);
        float4 v = reinterpret_cast<const float4*>(src)[i & 16383];
        u16x4 o;
        o[0] = f2bf(v.x); o[1] = f2bf(v.y); o[2] = f2bf(v.z); o[3] = f2bf(v.w);
        *reinterpret_cast<u16x4*>(whb + (size_t)i * 4) = o;
    } else {
        int i = (bid - 192) * 256 + threadIdx.x;   // float4 idx < 262144
        float4 v = reinterpret_cast<const float4*>(Wr)[i];
        u16x4 o;
        o[0] = f2bf(v.x); o[1] = f2bf(v.y); o[2] = f2bf(v.z); o[3] = f2bf(v.w);
        *reinterpret_cast<u16x4*>(wrb + (size_t)i * 4) = o;
    }
}

// ---------------- Kernel 1: QKV projection, plain bf16 MFMA ----------------
// One wave per block, dg-loop: both 32-d halves done by the same block so the
// x tile is loaded/converted once (halves x fp32 traffic vs one-dg blocks).
__global__ __launch_bounds__(64) void qkv_mfma(
    const float* __restrict__ x, const unsigned short* __restrict__ wb,
    const float* __restrict__ Er,
    unsigned short* __restrict__ qb_g, unsigned short* __restrict__ kh_g,
    unsigned short* __restrict__ vT_g)
{
    int bid = blockIdx.x;
    int tt = bid & 63;
    int h  = (bid >> 6) & 15;
    int b  = bid >> 10;
    int bh = b * H_DIM + h;
    int t0 = tt * 32;
    int lane = threadIdx.x;
    int l31 = lane & 31, hs = lane >> 5;

    bf16x8 xb[4];
    const float* xrow = x + (size_t)(t0 + l31) * (B_DIM * E_DIM) + (size_t)b * E_DIM + h * 64;
#pragma unroll
    for (int ks = 0; ks < 4; ++ks) {
        float vv[8];
        *reinterpret_cast<float4*>(&vv[0]) = *reinterpret_cast<const float4*>(xrow + ks * 16 + hs * 8);
        *reinterpret_cast<float4*>(&vv[4]) = *reinterpret_cast<const float4*>(xrow + ks * 16 + hs * 8 + 4);
        unsigned short hh[8];
#pragma unroll
        for (int j = 0; j < 8; ++j) hh[j] = f2bf(vv[j]);
        xb[ks] = *reinterpret_cast<bf16x8*>(hh);
    }

    size_t rowbase = (size_t)bh * T_DIM * 64;
#pragma unroll 1
    for (int dg = 0; dg < 2; ++dg) {
        f32x16 aq = zero16(), ak = zero16(), av = zero16();
        size_t wofs = (size_t)h * 4096 + (size_t)(dg * 32 + l31) * 64 + hs * 8;
#pragma unroll
        for (int ks = 0; ks < 4; ++ks) {
            bf16x8 qw = *reinterpret_cast<const bf16x8*>(wb + wofs + ks * 16);
            bf16x8 kw = *reinterpret_cast<const bf16x8*>(wb + 65536 + wofs + ks * 16);
            bf16x8 vw = *reinterpret_cast<const bf16x8*>(wb + 131072 + wofs + ks * 16);
            aq = MFMA32(xb[ks], qw, aq);
            ak = MFMA32(xb[ks], kw, ak);
            av = MFMA32(vw, xb[ks], av);   // v computed transposed: D = W*x^T
        }
#pragma unroll
        for (int r = 0; r < 16; ++r) {
            int rowp = (r & 3) + 8 * (r >> 2) + 4 * hs;
            int t = t0 + rowp;
            int d = dg * 32 + l31;
            size_t ro = rowbase + (size_t)t * 64 + d;
            qb_g[ro] = f2bf(aq[r]);
            float kv = (ak[r] * 0.03125f + Er[(size_t)d * T_DIM + t]) * LOG2E;
            kh_g[ro] = f2bf(kv);
            vT_g[((size_t)bh * 64 + dg * 32 + rowp) * T_DIM + t0 + l31] = f2bf(av[r]);
        }
    }
}

// ---------------- Kernel 2: causal flash attention ---------------------------
// 1024 blocks x 4 waves (256 thr): block = 64 q-rows (2 wq x 32q), 2-way
// K-split. Single-buffered LDS = 32768 B exactly -> 5 blocks/CU (ML merge
// scratch aliased into the KV region instead of exceeding 32KB).
// 2-deep subtile pipeline; deep swizzle; no-max softmax; in-LDS half merge;
// static quad-balanced qt map ({31-j, j, 23-j, 8+j} sums 62 for all j).
__global__ __launch_bounds__(256, 5) void attn_mfma32(
    const unsigned short* __restrict__ qb_g, const unsigned short* __restrict__ kh_g,
    const unsigned short* __restrict__ vT_g, unsigned short* __restrict__ attT)
{
    __shared__ __align__(16) unsigned char smem[32768];
    float* OT  = (float*)smem;            // [64][68] f32 epilogue (aliases KV)
    float* MRG = (float*)smem;            // [64][64] f32 = 16KB merge (aliases KV)
    float* ML  = (float*)(smem + 16384);  // [64] f32 (aliases KV half-1; safe:
                                          // merge runs after all compute barriers,
                                          // OT overwrite ordered after merge reads)

    int bid = blockIdx.x;
    int bh = bid & 31;            // bh%8 = XCD -> 4 heads/XCD, K/V L2-resident
    int u = bid >> 5;             // 0..31
    int j = u & 7, quad = u >> 3;
    int qt = (quad == 0) ? (31 - j) : (quad == 1) ? j
           : (quad == 2) ? (23 - j) : (8 + j);

    int tid = threadIdx.x;
    int w = tid >> 6;             // 0..3
    int half = w >> 1;            // K-split half
    int wq = w & 1;               // q sub-block
    int lane = tid & 63;
    int l31 = lane & 31, hs = lane >> 5;
    int srow = lane >> 3, scol = lane & 7;
    int lsw = (l31 & 7) ^ (((l31 >> 3) & 3) << 1);   // read-side row swizzle
    int q_lo = qt * 64 + wq * 32;
    size_t base = (size_t)bh * T_DIM * 64;

    // Q fragments (held in registers)
    bf16x8 qB[4];
    {
        size_t qoff = base + (size_t)(q_lo + l31) * 64 + hs * 8;
#pragma unroll
        for (int st = 0; st < 4; ++st)
            qB[st] = *reinterpret_cast<const bf16x8*>(qb_g + qoff + st * 16);
    }

    f32x16 oacc0 = zero16(), oacc1 = zero16();   // O^T: col=q(lane), regs=d
    float lsum = 0.f;

    unsigned char* KH = smem + half * 16384;     // [64 k][64 d] bf16, swizzled
    unsigned char* VT = KH + 8192;               // [64 d][64 k] bf16, swizzled

    // QK^T subtile: S^T = K' x Q, col=q=l31, regs=krow
    auto qk = [&](int kt) -> f32x16 {
        int krow = kt * 32 + l31;
        f32x16 s = zero16();
        __builtin_amdgcn_s_setprio(1);
#pragma unroll
        for (int st = 0; st < 4; ++st) {
            int slot = (st * 2 + hs) ^ lsw;
            bf16x8 kf = *reinterpret_cast<const bf16x8*>(KH + krow * 128 + slot * 16);
            s = MFMA32(kf, qB[st], s);
        }
        __builtin_amdgcn_s_setprio(0);
        return s;
    };

    // no-max softmax + P conversion + PV
    auto smpv = [&](f32x16& s, int kt, bool diag) {
        if (diag) {
#pragma unroll
            for (int r = 0; r < 16; ++r) {
                int rowp = (r & 3) + 8 * (r >> 2) + 4 * hs;
                if (rowp > l31) s[r] = -1e30f;   // mask krow > q (exp2 -> 0)
            }
        }
        float p[16], psum = 0.f;
#pragma unroll
        for (int r = 0; r < 16; ++r) {
            p[r] = __builtin_amdgcn_exp2f(s[r]);
            psum += p[r];
        }
        lsum += psum + __shfl_xor(psum, 32);
        unsigned int wp[8];
#pragma unroll
        for (int q2 = 0; q2 < 2; ++q2) {
            int o = q2 * 8, d2 = q2 * 4;
            asm("v_cvt_pk_bf16_f32 %0, %1, %2" : "=v"(wp[d2+0]) : "v"(p[o+0]), "v"(p[o+1]));
            asm("v_cvt_pk_bf16_f32 %0, %1, %2" : "=v"(wp[d2+1]) : "v"(p[o+2]), "v"(p[o+3]));
            asm("v_cvt_pk_bf16_f32 %0, %1, %2" : "=v"(wp[d2+2]) : "v"(p[o+4]), "v"(p[o+5]));
            asm("v_cvt_pk_bf16_f32 %0, %1, %2" : "=v"(wp[d2+3]) : "v"(p[o+6]), "v"(p[o+7]));
            asm("v_permlane32_swap_b32 %0, %1" : "+v"(wp[d2+0]), "+v"(wp[d2+2]));
            asm("v_permlane32_swap_b32 %0, %1" : "+v"(wp[d2+1]), "+v"(wp[d2+3]));
        }
        union { unsigned int u[4]; bf16x8 v; } pa0, pa1;
        pa0.u[0] = wp[0]; pa0.u[1] = wp[1]; pa0.u[2] = wp[2]; pa0.u[3] = wp[3];
        pa1.u[0] = wp[4]; pa1.u[1] = wp[5]; pa1.u[2] = wp[6]; pa1.u[3] = wp[7];
        __builtin_amdgcn_s_setprio(1);
#pragma unroll
        for (int ph = 0; ph < 2; ++ph) {
            const bf16x8 pv = ph ? pa1.v : pa0.v;
#pragma unroll
            for (int dt = 0; dt < 2; ++dt) {
                int c = kt * 4 + ph * 2 + hs;
                int slot = c ^ lsw;
                bf16x8 vb = *reinterpret_cast<const bf16x8*>(VT + (dt * 32 + l31) * 128 + slot * 16);
                if (dt == 0) oacc0 = MFMA32(vb, pv, oacc0);
                else         oacc1 = MFMA32(vb, pv, oacc1);
            }
        }
        __builtin_amdgcn_s_setprio(0);
    };

    int ntiles = qt + 1;              // 64-row K-tiles
    int nst = (ntiles + 1) >> 1;      // lockstep steps (half 1 may idle last)

    for (int i = 0; i < nst; ++i) {
        int k0 = (2 * i + half) * 64;
        bool valid = k0 < ntiles * 64;
        __syncthreads();              // prev compute done; LDS reusable
        if (valid) {
#pragma unroll
            for (int ci = 0; ci < 4; ++ci) {      // K tile 8KB
                int chunk = wq * 4 + ci;
                int row = chunk * 8 + srow;
                int cd = scol ^ srow ^ ((ci & 3) << 1);
                gload16(kh_g + base + (size_t)(k0 + row) * 64 + cd * 8,
                        KH + chunk * 1024 + lane * 16);
            }
#pragma unroll
            for (int ci = 0; ci < 4; ++ci) {      // V tile 8KB
                int chunk = wq * 4 + ci;
                int d = chunk * 8 + srow;
                int cd = scol ^ srow ^ ((ci & 3) << 1);
                gload16(vT_g + base + (size_t)d * T_DIM + k0 + cd * 8,
                        VT + chunk * 1024 + lane * 16);
            }
        }
        __syncthreads();              // staged data visible (vmcnt drain)
        if (valid) {
            // 2-deep subtile pipeline: both QK chains issued before softmax/PV
            bool two = (k0 + 32 <= q_lo);
            f32x16 s0 = qk(0);
            if (two) {
                f32x16 s1 = qk(1);
                smpv(s0, 0, false);               // k0 < q_lo here
                smpv(s1, 1, k0 + 32 == q_lo);
            } else {
                smpv(s0, 0, k0 == q_lo);
            }
        }
    }

    // ---- merge the two K-halves in-LDS (pure sums, layouts match) ----
    __syncthreads();                  // all compute done; KV region reusable
    if (half == 1) {
#pragma unroll
        for (int r = 0; r < 16; ++r) {
            MRG[(wq * 32 + r) * 64 + lane]      = oacc0[r];
            MRG[(wq * 32 + 16 + r) * 64 + lane] = oacc1[r];
        }
        if (hs == 0) ML[wq * 32 + l31] = lsum;
    }
    __syncthreads();
    float inv = 0.f;
    if (half == 0) {
        lsum += ML[wq * 32 + l31];
        inv = 1.f / lsum;
#pragma unroll
        for (int r = 0; r < 16; ++r) {
            oacc0[r] += MRG[(wq * 32 + r) * 64 + lane];
            oacc1[r] += MRG[(wq * 32 + 16 + r) * 64 + lane];
        }
    }
    __syncthreads();                  // merge reads done before OT overwrite

    // ---- epilogue: normalize, stage OT[d][q], store attT bf16 ----
    if (half == 0) {
#pragma unroll
        for (int r = 0; r < 16; ++r) {
            int rowp = (r & 3) + 8 * (r >> 2) + 4 * hs;   // d-row within 32
            OT[(rowp)      * 68 + wq * 32 + l31] = oacc0[r] * inv;
            OT[(32 + rowp) * 68 + wq * 32 + l31] = oacc1[r] * inv;
        }
    }
    __syncthreads();
    {
        int d = tid >> 2, qb = tid & 3;   // 64 d x 4 groups of 16 q
        unsigned short tmp[16];
#pragma unroll
        for (int i = 0; i < 4; ++i) {
            f32x4 v = *reinterpret_cast<const f32x4*>(&OT[d * 68 + qb * 16 + i * 4]);
            tmp[i*4+0] = f2bf(v[0]); tmp[i*4+1] = f2bf(v[1]);
            tmp[i*4+2] = f2bf(v[2]); tmp[i*4+3] = f2bf(v[3]);
        }
        unsigned short* dst = attT + ((size_t)bh * 64 + d) * T_DIM + qt * 64 + qb * 16;
        *reinterpret_cast<u16x8*>(dst)     = *reinterpret_cast<u16x8*>(&tmp[0]);
        *reinterpret_cast<u16x8*>(dst + 8) = *reinterpret_cast<u16x8*>(&tmp[8]);
    }
}

// ---------------- Kernel 3: out = attT(as [4096][1024]) @ Wr^T + br ----------
__global__ __launch_bounds__(256) void final_gemm_mfma(
    const unsigned short* __restrict__ A, const unsigned short* __restrict__ Bw,
    const float* __restrict__ br, float* __restrict__ out)
{
    __shared__ __align__(16) unsigned char gsm[49152];   // 2 x (A 16KB + B 8KB)
    int nt = blockIdx.x;
    int mt = blockIdx.y;
    int tid = threadIdx.x;
    int w = tid >> 6;
    int lane = tid & 63;
    int l31 = lane & 31, hs = lane >> 5;
    int srow = lane >> 3, scol = lane & 7;
    int lsw = (l31 & 7) ^ (((l31 >> 3) & 3) << 1);

    auto stage = [&](int bs, int kt) {
        unsigned char* As = gsm + bs * 24576;
        unsigned char* Bs = As + 16384;
#pragma unroll
        for (int i = 0; i < 4; ++i) {
            int row = i * 32 + w * 8 + srow;
            int cd = scol ^ srow ^ (((row >> 3) & 3) << 1);
            gload16(A + (size_t)(mt * 128 + row) * 1024 + kt * 64 + cd * 8,
                    As + i * 4096 + w * 1024 + lane * 16);
        }
#pragma unroll
        for (int i = 0; i < 2; ++i) {
            int row = i * 32 + w * 8 + srow;
            int cd = scol ^ srow ^ (((row >> 3) & 3) << 1);
            gload16(Bw + (size_t)(nt * 64 + row) * 1024 + kt * 64 + cd * 8,
                    Bs + i * 4096 + w * 1024 + lane * 16);
        }
    };

    f32x16 oa0 = zero16(), oa1 = zero16();
    stage(0, 0);
    __syncthreads();
    for (int kt = 0; kt < 16; ++kt) {
        if (kt < 15) stage((kt + 1) & 1, kt + 1);
        const unsigned char* As = gsm + (kt & 1) * 24576;
        const unsigned char* Bs = As + 16384;
        int arow = w * 32 + l31;
        int asw = (arow & 7) ^ (((arow >> 3) & 3) << 1);
        __builtin_amdgcn_s_setprio(1);
#pragma unroll
        for (int st = 0; st < 4; ++st) {
            int c = st * 2 + hs;
            bf16x8 af = *reinterpret_cast<const bf16x8*>(As + arow * 128 + ((c ^ asw) * 16));
            {
                bf16x8 bf0 = *reinterpret_cast<const bf16x8*>(Bs + l31 * 128 + ((c ^ lsw) * 16));
                oa0 = MFMA32(af, bf0, oa0);
            }
            {
                int brow = 32 + l31;
                bf16x8 bf1 = *reinterpret_cast<const bf16x8*>(Bs + brow * 128 + ((c ^ lsw) * 16));
                oa1 = MFMA32(af, bf1, oa1);
            }
        }
        __builtin_amdgcn_s_setprio(0);
        __syncthreads();
    }

#pragma unroll
    for (int ng = 0; ng < 2; ++ng) {
        int col = nt * 64 + ng * 32 + l31;
        float bias = br[col];
        const f32x16& oa = ng ? oa1 : oa0;
#pragma unroll
        for (int r = 0; r < 16; ++r) {
            int rowp = (r & 3) + 8 * (r >> 2) + 4 * hs;
            int row = mt * 128 + w * 32 + rowp;
            out[(size_t)row * 1024 + col] = oa[r] + bias;
        }
    }
}

extern "C" void kernel_launch(void* const* d_in, const int* in_sizes, int n_in,
                              void* d_out, int out_size, void* d_ws, size_t ws_size,
                              hipStream_t stream) {
    const float* x  = (const float*)d_in[0];
    const float* Wq = (const float*)d_in[1];
    const float* Wk = (const float*)d_in[2];
    const float* Wv = (const float*)d_in[3];
    const float* Er = (const float*)d_in[4];
    const float* Wr = (const float*)d_in[5];
    const float* br = (const float*)d_in[6];
    float* out = (float*)d_out;

    const size_t nQ = (size_t)B_DIM * H_DIM * T_DIM * S_DIM;   // 4,194,304
    char* p = (char*)d_ws;
    unsigned short* qb = (unsigned short*)p;   p += nQ * 2;
    unsigned short* kh = (unsigned short*)p;   p += nQ * 2;
    unsigned short* vT = (unsigned short*)p;   p += nQ * 2;
    unsigned short* attT = (unsigned short*)p; p += nQ * 2;
    unsigned short* wrb = (unsigned short*)p;  p += (size_t)E_DIM * E_DIM * 2;
    unsigned short* whb = (unsigned short*)p;  p += (size_t)3 * 65536 * 2;
    size_t need = (size_t)(p - (char*)d_ws);
    if (ws_size < need) {
        fprintf(stderr, "WS TOO SMALL: have %zu need %zu\n", ws_size, need);
        return;
    }

    prep_w<<<1216, 256, 0, stream>>>(Wq, Wk, Wv, Wr, whb, wrb);
    qkv_mfma<<<2048, 64, 0, stream>>>(x, whb, Er, qb, kh, vT);
    attn_mfma32<<<1024, 256, 0, stream>>>(qb, kh, vT, attT);
    final_gemm_mfma<<<dim3(16, 32), 256, 0, stream>>>(attT, wrb, br, out);
}

// Round 15
// 72.999 us; speedup vs baseline: 1.5969x; 1.5969x over previous
//
#include <hip/hip_runtime.h>
#include <hip/hip_bf16.h>
#include <cstdio>

#define T_DIM 2048
#define B_DIM 2
#define E_DIM 1024
#define H_DIM 16
#define S_DIM 64
#define LOG2E 1.44269504088896340736f

typedef __attribute__((ext_vector_type(4))) float f32x4;
typedef __attribute__((ext_vector_type(16))) float f32x16;
typedef __attribute__((ext_vector_type(8))) short bf16x8;
typedef __attribute__((ext_vector_type(8))) unsigned short u16x8;
typedef __attribute__((ext_vector_type(4))) unsigned short u16x4;

#define MFMA32(a,b,c) __builtin_amdgcn_mfma_f32_32x32x16_bf16((a),(b),(c),0,0,0)

__device__ __forceinline__ unsigned short f2bf(float f) {
    union { __hip_bfloat16 h; unsigned short u; } c;
    c.h = __float2bfloat16(f);
    return c.u;
}
__device__ __forceinline__ void gload16(const void* g, void* l) {
    __builtin_amdgcn_global_load_lds(
        (const __attribute__((address_space(1))) unsigned int*)g,
        (__attribute__((address_space(3))) unsigned int*)l, 16, 0, 0);
}
__device__ __forceinline__ f32x16 zero16() {
    f32x16 v;
#pragma unroll
    for (int i = 0; i < 16; ++i) v[i] = 0.f;
    return v;
}

// ---------------- Kernel 0: weight prep (all weights -> bf16) ----------------
__global__ __launch_bounds__(256) void prep_w(
    const float* __restrict__ Wq, const float* __restrict__ Wk,
    const float* __restrict__ Wv, const float* __restrict__ Wr,
    unsigned short* __restrict__ whb, unsigned short* __restrict__ wrb)
{
    int bid = blockIdx.x;
    if (bid < 192) {
        int i = bid * 256 + threadIdx.x;   // float4 idx < 49152
        const float* src = (i < 16384) ? Wq : ((i < 32768) ? Wk : Wv);
        float4 v = reinterpret_cast<const float4*>(src)[i & 16383];
        u16x4 o;
        o[0] = f2bf(v.x); o[1] = f2bf(v.y); o[2] = f2bf(v.z); o[3] = f2bf(v.w);
        *reinterpret_cast<u16x4*>(whb + (size_t)i * 4) = o;
    } else {
        int i = (bid - 192) * 256 + threadIdx.x;   // float4 idx < 262144
        float4 v = reinterpret_cast<const float4*>(Wr)[i];
        u16x4 o;
        o[0] = f2bf(v.x); o[1] = f2bf(v.y); o[2] = f2bf(v.z); o[3] = f2bf(v.w);
        *reinterpret_cast<u16x4*>(wrb + (size_t)i * 4) = o;
    }
}

// ---------------- Kernel 1: QKV projection, plain bf16 MFMA ----------------
// One wave per block, dg-loop: both 32-d halves done by the same block so the
// x tile is loaded/converted once (halves x fp32 traffic vs one-dg blocks).
__global__ __launch_bounds__(64) void qkv_mfma(
    const float* __restrict__ x, const unsigned short* __restrict__ wb,
    const float* __restrict__ Er,
    unsigned short* __restrict__ qb_g, unsigned short* __restrict__ kh_g,
    unsigned short* __restrict__ vT_g)
{
    int bid = blockIdx.x;
    int tt = bid & 63;
    int h  = (bid >> 6) & 15;
    int b  = bid >> 10;
    int bh = b * H_DIM + h;
    int t0 = tt * 32;
    int lane = threadIdx.x;
    int l31 = lane & 31, hs = lane >> 5;

    bf16x8 xb[4];
    const float* xrow = x + (size_t)(t0 + l31) * (B_DIM * E_DIM) + (size_t)b * E_DIM + h * 64;
#pragma unroll
    for (int ks = 0; ks < 4; ++ks) {
        float vv[8];
        *reinterpret_cast<float4*>(&vv[0]) = *reinterpret_cast<const float4*>(xrow + ks * 16 + hs * 8);
        *reinterpret_cast<float4*>(&vv[4]) = *reinterpret_cast<const float4*>(xrow + ks * 16 + hs * 8 + 4);
        unsigned short hh[8];
#pragma unroll
        for (int j = 0; j < 8; ++j) hh[j] = f2bf(vv[j]);
        xb[ks] = *reinterpret_cast<bf16x8*>(hh);
    }

    size_t rowbase = (size_t)bh * T_DIM * 64;
#pragma unroll 1
    for (int dg = 0; dg < 2; ++dg) {
        f32x16 aq = zero16(), ak = zero16(), av = zero16();
        size_t wofs = (size_t)h * 4096 + (size_t)(dg * 32 + l31) * 64 + hs * 8;
#pragma unroll
        for (int ks = 0; ks < 4; ++ks) {
            bf16x8 qw = *reinterpret_cast<const bf16x8*>(wb + wofs + ks * 16);
            bf16x8 kw = *reinterpret_cast<const bf16x8*>(wb + 65536 + wofs + ks * 16);
            bf16x8 vw = *reinterpret_cast<const bf16x8*>(wb + 131072 + wofs + ks * 16);
            aq = MFMA32(xb[ks], qw, aq);
            ak = MFMA32(xb[ks], kw, ak);
            av = MFMA32(vw, xb[ks], av);   // v computed transposed: D = W*x^T
        }
#pragma unroll
        for (int r = 0; r < 16; ++r) {
            int rowp = (r & 3) + 8 * (r >> 2) + 4 * hs;
            int t = t0 + rowp;
            int d = dg * 32 + l31;
            size_t ro = rowbase + (size_t)t * 64 + d;
            qb_g[ro] = f2bf(aq[r]);
            float kv = (ak[r] * 0.03125f + Er[(size_t)d * T_DIM + t]) * LOG2E;
            kh_g[ro] = f2bf(kv);
            vT_g[((size_t)bh * 64 + dg * 32 + rowp) * T_DIM + t0 + l31] = f2bf(av[r]);
        }
    }
}

// ---------------- Kernel 2: causal flash attention ---------------------------
// 1024 blocks x 4 waves (256 thr): block = 64 q-rows (2 wq x 32q), 2-way
// K-split. Single-buffered LDS = 32768 B exactly -> 5 blocks/CU at runtime
// (LDS-limited; VGPR ~64 allows 8 waves/SIMD). NOTE: declare bounds (256,4)
// only — declaring 5 waves/EU capped VGPR to 48 and spilled oacc (R14:
// WRITE_SIZE 87MB, 1.6x regression). Runtime occupancy is resource-driven.
// 2-deep subtile pipeline; deep swizzle; no-max softmax; in-LDS half merge;
// static quad-balanced qt map ({31-j, j, 23-j, 8+j} sums 62 for all j).
__global__ __launch_bounds__(256, 4) void attn_mfma32(
    const unsigned short* __restrict__ qb_g, const unsigned short* __restrict__ kh_g,
    const unsigned short* __restrict__ vT_g, unsigned short* __restrict__ attT)
{
    __shared__ __align__(16) unsigned char smem[32768];
    float* OT  = (float*)smem;            // [64][68] f32 epilogue (aliases KV)
    float* MRG = (float*)smem;            // [64][64] f32 = 16KB merge (aliases KV)
    float* ML  = (float*)(smem + 16384);  // [64] f32 (aliases KV half-1; safe:
                                          // merge runs after all compute barriers,
                                          // OT overwrite ordered after merge reads)

    int bid = blockIdx.x;
    int bh = bid & 31;            // bh%8 = XCD -> 4 heads/XCD, K/V L2-resident
    int u = bid >> 5;             // 0..31
    int j = u & 7, quad = u >> 3;
    int qt = (quad == 0) ? (31 - j) : (quad == 1) ? j
           : (quad == 2) ? (23 - j) : (8 + j);

    int tid = threadIdx.x;
    int w = tid >> 6;             // 0..3
    int half = w >> 1;            // K-split half
    int wq = w & 1;               // q sub-block
    int lane = tid & 63;
    int l31 = lane & 31, hs = lane >> 5;
    int srow = lane >> 3, scol = lane & 7;
    int lsw = (l31 & 7) ^ (((l31 >> 3) & 3) << 1);   // read-side row swizzle
    int q_lo = qt * 64 + wq * 32;
    size_t base = (size_t)bh * T_DIM * 64;

    // Q fragments (held in registers)
    bf16x8 qB[4];
    {
        size_t qoff = base + (size_t)(q_lo + l31) * 64 + hs * 8;
#pragma unroll
        for (int st = 0; st < 4; ++st)
            qB[st] = *reinterpret_cast<const bf16x8*>(qb_g + qoff + st * 16);
    }

    f32x16 oacc0 = zero16(), oacc1 = zero16();   // O^T: col=q(lane), regs=d
    float lsum = 0.f;

    unsigned char* KH = smem + half * 16384;     // [64 k][64 d] bf16, swizzled
    unsigned char* VT = KH + 8192;               // [64 d][64 k] bf16, swizzled

    // QK^T subtile: S^T = K' x Q, col=q=l31, regs=krow
    auto qk = [&](int kt) -> f32x16 {
        int krow = kt * 32 + l31;
        f32x16 s = zero16();
        __builtin_amdgcn_s_setprio(1);
#pragma unroll
        for (int st = 0; st < 4; ++st) {
            int slot = (st * 2 + hs) ^ lsw;
            bf16x8 kf = *reinterpret_cast<const bf16x8*>(KH + krow * 128 + slot * 16);
            s = MFMA32(kf, qB[st], s);
        }
        __builtin_amdgcn_s_setprio(0);
        return s;
    };

    // no-max softmax + P conversion + PV
    auto smpv = [&](f32x16& s, int kt, bool diag) {
        if (diag) {
#pragma unroll
            for (int r = 0; r < 16; ++r) {
                int rowp = (r & 3) + 8 * (r >> 2) + 4 * hs;
                if (rowp > l31) s[r] = -1e30f;   // mask krow > q (exp2 -> 0)
            }
        }
        float p[16], psum = 0.f;
#pragma unroll
        for (int r = 0; r < 16; ++r) {
            p[r] = __builtin_amdgcn_exp2f(s[r]);
            psum += p[r];
        }
        lsum += psum + __shfl_xor(psum, 32);
        unsigned int wp[8];
#pragma unroll
        for (int q2 = 0; q2 < 2; ++q2) {
            int o = q2 * 8, d2 = q2 * 4;
            asm("v_cvt_pk_bf16_f32 %0, %1, %2" : "=v"(wp[d2+0]) : "v"(p[o+0]), "v"(p[o+1]));
            asm("v_cvt_pk_bf16_f32 %0, %1, %2" : "=v"(wp[d2+1]) : "v"(p[o+2]), "v"(p[o+3]));
            asm("v_cvt_pk_bf16_f32 %0, %1, %2" : "=v"(wp[d2+2]) : "v"(p[o+4]), "v"(p[o+5]));
            asm("v_cvt_pk_bf16_f32 %0, %1, %2" : "=v"(wp[d2+3]) : "v"(p[o+6]), "v"(p[o+7]));
            asm("v_permlane32_swap_b32 %0, %1" : "+v"(wp[d2+0]), "+v"(wp[d2+2]));
            asm("v_permlane32_swap_b32 %0, %1" : "+v"(wp[d2+1]), "+v"(wp[d2+3]));
        }
        union { unsigned int u[4]; bf16x8 v; } pa0, pa1;
        pa0.u[0] = wp[0]; pa0.u[1] = wp[1]; pa0.u[2] = wp[2]; pa0.u[3] = wp[3];
        pa1.u[0] = wp[4]; pa1.u[1] = wp[5]; pa1.u[2] = wp[6]; pa1.u[3] = wp[7];
        __builtin_amdgcn_s_setprio(1);
#pragma unroll
        for (int ph = 0; ph < 2; ++ph) {
            const bf16x8 pv = ph ? pa1.v : pa0.v;
#pragma unroll
            for (int dt = 0; dt < 2; ++dt) {
                int c = kt * 4 + ph * 2 + hs;
                int slot = c ^ lsw;
                bf16x8 vb = *reinterpret_cast<const bf16x8*>(VT + (dt * 32 + l31) * 128 + slot * 16);
                if (dt == 0) oacc0 = MFMA32(vb, pv, oacc0);
                else         oacc1 = MFMA32(vb, pv, oacc1);
            }
        }
        __builtin_amdgcn_s_setprio(0);
    };

    int ntiles = qt + 1;              // 64-row K-tiles
    int nst = (ntiles + 1) >> 1;      // lockstep steps (half 1 may idle last)

    for (int i = 0; i < nst; ++i) {
        int k0 = (2 * i + half) * 64;
        bool valid = k0 < ntiles * 64;
        __syncthreads();              // prev compute done; LDS reusable
        if (valid) {
#pragma unroll
            for (int ci = 0; ci < 4; ++ci) {      // K tile 8KB
                int chunk = wq * 4 + ci;
                int row = chunk * 8 + srow;
                int cd = scol ^ srow ^ ((ci & 3) << 1);
                gload16(kh_g + base + (size_t)(k0 + row) * 64 + cd * 8,
                        KH + chunk * 1024 + lane * 16);
            }
#pragma unroll
            for (int ci = 0; ci < 4; ++ci) {      // V tile 8KB
                int chunk = wq * 4 + ci;
                int d = chunk * 8 + srow;
                int cd = scol ^ srow ^ ((ci & 3) << 1);
                gload16(vT_g + base + (size_t)d * T_DIM + k0 + cd * 8,
                        VT + chunk * 1024 + lane * 16);
            }
        }
        __syncthreads();              // staged data visible (vmcnt drain)
        if (valid) {
            // 2-deep subtile pipeline: both QK chains issued before softmax/PV
            bool two = (k0 + 32 <= q_lo);
            f32x16 s0 = qk(0);
            if (two) {
                f32x16 s1 = qk(1);
                smpv(s0, 0, false);               // k0 < q_lo here
                smpv(s1, 1, k0 + 32 == q_lo);
            } else {
                smpv(s0, 0, k0 == q_lo);
            }
        }
    }

    // ---- merge the two K-halves in-LDS (pure sums, layouts match) ----
    __syncthreads();                  // all compute done; KV region reusable
    if (half == 1) {
#pragma unroll
        for (int r = 0; r < 16; ++r) {
            MRG[(wq * 32 + r) * 64 + lane]      = oacc0[r];
            MRG[(wq * 32 + 16 + r) * 64 + lane] = oacc1[r];
        }
        if (hs == 0) ML[wq * 32 + l31] = lsum;
    }
    __syncthreads();
    float inv = 0.f;
    if (half == 0) {
        lsum += ML[wq * 32 + l31];
        inv = 1.f / lsum;
#pragma unroll
        for (int r = 0; r < 16; ++r) {
            oacc0[r] += MRG[(wq * 32 + r) * 64 + lane];
            oacc1[r] += MRG[(wq * 32 + 16 + r) * 64 + lane];
        }
    }
    __syncthreads();                  // merge reads done before OT overwrite

    // ---- epilogue: normalize, stage OT[d][q], store attT bf16 ----
    if (half == 0) {
#pragma unroll
        for (int r = 0; r < 16; ++r) {
            int rowp = (r & 3) + 8 * (r >> 2) + 4 * hs;   // d-row within 32
            OT[(rowp)      * 68 + wq * 32 + l31] = oacc0[r] * inv;
            OT[(32 + rowp) * 68 + wq * 32 + l31] = oacc1[r] * inv;
        }
    }
    __syncthreads();
    {
        int d = tid >> 2, qb = tid & 3;   // 64 d x 4 groups of 16 q
        unsigned short tmp[16];
#pragma unroll
        for (int i = 0; i < 4; ++i) {
            f32x4 v = *reinterpret_cast<const f32x4*>(&OT[d * 68 + qb * 16 + i * 4]);
            tmp[i*4+0] = f2bf(v[0]); tmp[i*4+1] = f2bf(v[1]);
            tmp[i*4+2] = f2bf(v[2]); tmp[i*4+3] = f2bf(v[3]);
        }
        unsigned short* dst = attT + ((size_t)bh * 64 + d) * T_DIM + qt * 64 + qb * 16;
        *reinterpret_cast<u16x8*>(dst)     = *reinterpret_cast<u16x8*>(&tmp[0]);
        *reinterpret_cast<u16x8*>(dst + 8) = *reinterpret_cast<u16x8*>(&tmp[8]);
    }
}

// ---------------- Kernel 3: out = attT(as [4096][1024]) @ Wr^T + br ----------
__global__ __launch_bounds__(256) void final_gemm_mfma(
    const unsigned short* __restrict__ A, const unsigned short* __restrict__ Bw,
    const float* __restrict__ br, float* __restrict__ out)
{
    __shared__ __align__(16) unsigned char gsm[49152];   // 2 x (A 16KB + B 8KB)
    int nt = blockIdx.x;
    int mt = blockIdx.y;
    int tid = threadIdx.x;
    int w = tid >> 6;
    int lane = tid & 63;
    int l31 = lane & 31, hs = lane >> 5;
    int srow = lane >> 3, scol = lane & 7;
    int lsw = (l31 & 7) ^ (((l31 >> 3) & 3) << 1);

    auto stage = [&](int bs, int kt) {
        unsigned char* As = gsm + bs * 24576;
        unsigned char* Bs = As + 16384;
#pragma unroll
        for (int i = 0; i < 4; ++i) {
            int row = i * 32 + w * 8 + srow;
            int cd = scol ^ srow ^ (((row >> 3) & 3) << 1);
            gload16(A + (size_t)(mt * 128 + row) * 1024 + kt * 64 + cd * 8,
                    As + i * 4096 + w * 1024 + lane * 16);
        }
#pragma unroll
        for (int i = 0; i < 2; ++i) {
            int row = i * 32 + w * 8 + srow;
            int cd = scol ^ srow ^ (((row >> 3) & 3) << 1);
            gload16(Bw + (size_t)(nt * 64 + row) * 1024 + kt * 64 + cd * 8,
                    Bs + i * 4096 + w * 1024 + lane * 16);
        }
    };

    f32x16 oa0 = zero16(), oa1 = zero16();
    stage(0, 0);
    __syncthreads();
    for (int kt = 0; kt < 16; ++kt) {
        if (kt < 15) stage((kt + 1) & 1, kt + 1);
        const unsigned char* As = gsm + (kt & 1) * 24576;
        const unsigned char* Bs = As + 16384;
        int arow = w * 32 + l31;
        int asw = (arow & 7) ^ (((arow >> 3) & 3) << 1);
        __builtin_amdgcn_s_setprio(1);
#pragma unroll
        for (int st = 0; st < 4; ++st) {
            int c = st * 2 + hs;
            bf16x8 af = *reinterpret_cast<const bf16x8*>(As + arow * 128 + ((c ^ asw) * 16));
            {
                bf16x8 bf0 = *reinterpret_cast<const bf16x8*>(Bs + l31 * 128 + ((c ^ lsw) * 16));
                oa0 = MFMA32(af, bf0, oa0);
            }
            {
                int brow = 32 + l31;
                bf16x8 bf1 = *reinterpret_cast<const bf16x8*>(Bs + brow * 128 + ((c ^ lsw) * 16));
                oa1 = MFMA32(af, bf1, oa1);
            }
        }
        __builtin_amdgcn_s_setprio(0);
        __syncthreads();
    }

#pragma unroll
    for (int ng = 0; ng < 2; ++ng) {
        int col = nt * 64 + ng * 32 + l31;
        float bias = br[col];
        const f32x16& oa = ng ? oa1 : oa0;
#pragma unroll
        for (int r = 0; r < 16; ++r) {
            int rowp = (r & 3) + 8 * (r >> 2) + 4 * hs;
            int row = mt * 128 + w * 32 + rowp;
            out[(size_t)row * 1024 + col] = oa[r] + bias;
        }
    }
}

extern "C" void kernel_launch(void* const* d_in, const int* in_sizes, int n_in,
                              void* d_out, int out_size, void* d_ws, size_t ws_size,
                              hipStream_t stream) {
    const float* x  = (const float*)d_in[0];
    const float* Wq = (const float*)d_in[1];
    const float* Wk = (const float*)d_in[2];
    const float* Wv = (const float*)d_in[3];
    const float* Er = (const float*)d_in[4];
    const float* Wr = (const float*)d_in[5];
    const float* br = (const float*)d_in[6];
    float* out = (float*)d_out;

    const size_t nQ = (size_t)B_DIM * H_DIM * T_DIM * S_DIM;   // 4,194,304
    char* p = (char*)d_ws;
    unsigned short* qb = (unsigned short*)p;   p += nQ * 2;
    unsigned short* kh = (unsigned short*)p;   p += nQ * 2;
    unsigned short* vT = (unsigned short*)p;   p += nQ * 2;
    unsigned short* attT = (unsigned short*)p; p += nQ * 2;
    unsigned short* wrb = (unsigned short*)p;  p += (size_t)E_DIM * E_DIM * 2;
    unsigned short* whb = (unsigned short*)p;  p += (size_t)3 * 65536 * 2;
    size_t need = (size_t)(p - (char*)d_ws);
    if (ws_size < need) {
        fprintf(stderr, "WS TOO SMALL: have %zu need %zu\n", ws_size, need);
        return;
    }

    prep_w<<<1216, 256, 0, stream>>>(Wq, Wk, Wv, Wr, whb, wrb);
    qkv_mfma<<<2048, 64, 0, stream>>>(x, whb, Er, qb, kh, vT);
    attn_mfma32<<<1024, 256, 0, stream>>>(qb, kh, vT, attT);
    final_gemm_mfma<<<dim3(16, 32), 256, 0, stream>>>(attT, wrb, br, out);
}

// Round 16
// 72.171 us; speedup vs baseline: 1.6152x; 1.0115x over previous
//
#include <hip/hip_runtime.h>
#include <hip/hip_bf16.h>
#include <cstdio>

#define T_DIM 2048
#define B_DIM 2
#define E_DIM 1024
#define H_DIM 16
#define S_DIM 64
#define LOG2E 1.44269504088896340736f

typedef __attribute__((ext_vector_type(4))) float f32x4;
typedef __attribute__((ext_vector_type(16))) float f32x16;
typedef __attribute__((ext_vector_type(8))) short bf16x8;
typedef __attribute__((ext_vector_type(8))) unsigned short u16x8;
typedef __attribute__((ext_vector_type(4))) unsigned short u16x4;

#define MFMA32(a,b,c) __builtin_amdgcn_mfma_f32_32x32x16_bf16((a),(b),(c),0,0,0)

__device__ __forceinline__ unsigned short f2bf(float f) {
    union { __hip_bfloat16 h; unsigned short u; } c;
    c.h = __float2bfloat16(f);
    return c.u;
}
__device__ __forceinline__ void gload16(const void* g, void* l) {
    __builtin_amdgcn_global_load_lds(
        (const __attribute__((address_space(1))) unsigned int*)g,
        (__attribute__((address_space(3))) unsigned int*)l, 16, 0, 0);
}
__device__ __forceinline__ f32x16 zero16() {
    f32x16 v;
#pragma unroll
    for (int i = 0; i < 16; ++i) v[i] = 0.f;
    return v;
}

// ---------------- Kernel 0: weight prep (all weights -> bf16) ----------------
__global__ __launch_bounds__(256) void prep_w(
    const float* __restrict__ Wq, const float* __restrict__ Wk,
    const float* __restrict__ Wv, const float* __restrict__ Wr,
    unsigned short* __restrict__ whb, unsigned short* __restrict__ wrb)
{
    int bid = blockIdx.x;
    if (bid < 192) {
        int i = bid * 256 + threadIdx.x;   // float4 idx < 49152
        const float* src = (i < 16384) ? Wq : ((i < 32768) ? Wk : Wv);
        float4 v = reinterpret_cast<const float4*>(src)[i & 16383];
        u16x4 o;
        o[0] = f2bf(v.x); o[1] = f2bf(v.y); o[2] = f2bf(v.z); o[3] = f2bf(v.w);
        *reinterpret_cast<u16x4*>(whb + (size_t)i * 4) = o;
    } else {
        int i = (bid - 192) * 256 + threadIdx.x;   // float4 idx < 262144
        float4 v = reinterpret_cast<const float4*>(Wr)[i];
        u16x4 o;
        o[0] = f2bf(v.x); o[1] = f2bf(v.y); o[2] = f2bf(v.z); o[3] = f2bf(v.w);
        *reinterpret_cast<u16x4*>(wrb + (size_t)i * 4) = o;
    }
}

// ---------------- Kernel 1: QKV projection, plain bf16 MFMA ----------------
// One wave per block, dg-loop: both 32-d halves done by the same block so the
// x tile is loaded/converted once.
__global__ __launch_bounds__(64) void qkv_mfma(
    const float* __restrict__ x, const unsigned short* __restrict__ wb,
    const float* __restrict__ Er,
    unsigned short* __restrict__ qb_g, unsigned short* __restrict__ kh_g,
    unsigned short* __restrict__ vT_g)
{
    int bid = blockIdx.x;
    int tt = bid & 63;
    int h  = (bid >> 6) & 15;
    int b  = bid >> 10;
    int bh = b * H_DIM + h;
    int t0 = tt * 32;
    int lane = threadIdx.x;
    int l31 = lane & 31, hs = lane >> 5;

    bf16x8 xb[4];
    const float* xrow = x + (size_t)(t0 + l31) * (B_DIM * E_DIM) + (size_t)b * E_DIM + h * 64;
#pragma unroll
    for (int ks = 0; ks < 4; ++ks) {
        float vv[8];
        *reinterpret_cast<float4*>(&vv[0]) = *reinterpret_cast<const float4*>(xrow + ks * 16 + hs * 8);
        *reinterpret_cast<float4*>(&vv[4]) = *reinterpret_cast<const float4*>(xrow + ks * 16 + hs * 8 + 4);
        unsigned short hh[8];
#pragma unroll
        for (int j = 0; j < 8; ++j) hh[j] = f2bf(vv[j]);
        xb[ks] = *reinterpret_cast<bf16x8*>(hh);
    }

    size_t rowbase = (size_t)bh * T_DIM * 64;
#pragma unroll 1
    for (int dg = 0; dg < 2; ++dg) {
        f32x16 aq = zero16(), ak = zero16(), av = zero16();
        size_t wofs = (size_t)h * 4096 + (size_t)(dg * 32 + l31) * 64 + hs * 8;
#pragma unroll
        for (int ks = 0; ks < 4; ++ks) {
            bf16x8 qw = *reinterpret_cast<const bf16x8*>(wb + wofs + ks * 16);
            bf16x8 kw = *reinterpret_cast<const bf16x8*>(wb + 65536 + wofs + ks * 16);
            bf16x8 vw = *reinterpret_cast<const bf16x8*>(wb + 131072 + wofs + ks * 16);
            aq = MFMA32(xb[ks], qw, aq);
            ak = MFMA32(xb[ks], kw, ak);
            av = MFMA32(vw, xb[ks], av);   // v computed transposed: D = W*x^T
        }
#pragma unroll
        for (int r = 0; r < 16; ++r) {
            int rowp = (r & 3) + 8 * (r >> 2) + 4 * hs;
            int t = t0 + rowp;
            int d = dg * 32 + l31;
            size_t ro = rowbase + (size_t)t * 64 + d;
            qb_g[ro] = f2bf(aq[r]);
            float kv = (ak[r] * 0.03125f + Er[(size_t)d * T_DIM + t]) * LOG2E;
            kh_g[ro] = f2bf(kv);
            vT_g[((size_t)bh * 64 + dg * 32 + rowp) * T_DIM + t0 + l31] = f2bf(av[r]);
        }
    }
}

// ---------------- Kernel 2: causal flash attention ---------------------------
// 1024 blocks x 4 waves (256 thr): block = 64 q-rows (2 wq x 32q), 2-way
// K-split over 32-row K-tiles. DOUBLE-BUFFERED prefetch-before-compute in
// 32768 B exactly (per half: 2 bufs x (K 4KB + V 4KB)) -> 5 blocks/CU AND
// stage(i+1) hides under compute(i) (the r12-r15 single-buffer structure
// fully exposed stage latency: barrier-stage-barrier-compute).
// Bounds stay (256,4): declaring 5 waves/EU capped VGPR->48 and spilled (R14).
// No-max softmax; in-LDS half merge; static quad-balanced qt map.
__global__ __launch_bounds__(256, 4) void attn_mfma32(
    const unsigned short* __restrict__ qb_g, const unsigned short* __restrict__ kh_g,
    const unsigned short* __restrict__ vT_g, unsigned short* __restrict__ attT)
{
    __shared__ __align__(16) unsigned char smem[32768];
    float* OT  = (float*)smem;            // [64][68] f32 epilogue (aliases KV)
    float* MRG = (float*)smem;            // [64][64] f32 = 16KB merge (aliases KV)
    float* ML  = (float*)(smem + 16384);  // [64] f32 (aliases half-1 bufs; safe:
                                          // used only after final compute barrier)

    int bid = blockIdx.x;
    int bh = bid & 31;            // bh%8 = XCD -> 4 heads/XCD, K/V L2-resident
    int u = bid >> 5;             // 0..31
    int j = u & 7, quad = u >> 3;
    int qt = (quad == 0) ? (31 - j) : (quad == 1) ? j
           : (quad == 2) ? (23 - j) : (8 + j);

    int tid = threadIdx.x;
    int w = tid >> 6;             // 0..3
    int half = w >> 1;            // K-split half (32-row tiles, parity = half)
    int wq = w & 1;               // q sub-block
    int lane = tid & 63;
    int l31 = lane & 31, hs = lane >> 5;
    int srow = lane >> 3, scol = lane & 7;       // K staging split
    int vrow = lane >> 2, vcol = lane & 3;       // V staging split
    int lsw = (l31 & 7) ^ (((l31 >> 3) & 3) << 1);   // K read-side row swizzle
    int q_lo = qt * 64 + wq * 32;
    size_t base = (size_t)bh * T_DIM * 64;

    // Q fragments (held in registers)
    bf16x8 qB[4];
    {
        size_t qoff = base + (size_t)(q_lo + l31) * 64 + hs * 8;
#pragma unroll
        for (int st = 0; st < 4; ++st)
            qB[st] = *reinterpret_cast<const bf16x8*>(qb_g + qoff + st * 16);
    }

    f32x16 oacc0 = zero16(), oacc1 = zero16();   // O^T: col=q(lane), regs=d
    float lsum = 0.f;

    unsigned char* hbase = smem + half * 16384;  // this half's 2 buffers

    // stage one 32-row K-tile (4KB) + V^T slice (4KB) into buffer bs
    auto stage = [&](int bs, int k0) {
        unsigned char* KH = hbase + bs * 8192;
        unsigned char* VT = KH + 4096;
#pragma unroll
        for (int ci = 0; ci < 2; ++ci) {          // K: 32 rows x 128 B
            int row = ci * 16 + wq * 8 + srow;
            int swz = (row & 7) ^ (((row >> 3) & 3) << 1);
            gload16(kh_g + base + (size_t)(k0 + row) * 64 + (scol ^ swz) * 8,
                    KH + ci * 2048 + wq * 1024 + lane * 16);
        }
#pragma unroll
        for (int ci = 0; ci < 2; ++ci) {          // V: 64 d-rows x 64 B
            int d = ci * 32 + wq * 16 + vrow;
            int swz = (d >> 1) & 3;
            gload16(vT_g + base + (size_t)d * T_DIM + k0 + ((vcol ^ swz) & 3) * 8,
                    VT + ci * 2048 + wq * 1024 + lane * 16);
        }
    };

    // compute one 32-row subtile from buffer bs
    auto compute = [&](int bs, int k0) {
        const unsigned char* KH = hbase + bs * 8192;
        const unsigned char* VT = KH + 4096;
        // ---- S^T = K' x Q: col=q=l31, regs=krow ----
        f32x16 s = zero16();
        __builtin_amdgcn_s_setprio(1);
#pragma unroll
        for (int st = 0; st < 4; ++st) {
            int slot = (st * 2 + hs) ^ lsw;
            bf16x8 kf = *reinterpret_cast<const bf16x8*>(KH + l31 * 128 + slot * 16);
            s = MFMA32(kf, qB[st], s);
        }
        __builtin_amdgcn_s_setprio(0);
        if (k0 == q_lo) {                         // diagonal subtile mask
#pragma unroll
            for (int r = 0; r < 16; ++r) {
                int rowp = (r & 3) + 8 * (r >> 2) + 4 * hs;
                if (rowp > l31) s[r] = -1e30f;
            }
        }
        // ---- no-max softmax (log2-scores fit fp32 exp2 range) ----
        float p[16], psum = 0.f;
#pragma unroll
        for (int r = 0; r < 16; ++r) {
            p[r] = __builtin_amdgcn_exp2f(s[r]);
            psum += p[r];
        }
        lsum += psum + __shfl_xor(psum, 32);
        // ---- P -> bf16 in-register (cvt_pk + permlane32_swap) ----
        unsigned int wp[8];
#pragma unroll
        for (int q2 = 0; q2 < 2; ++q2) {
            int o = q2 * 8, d2 = q2 * 4;
            asm("v_cvt_pk_bf16_f32 %0, %1, %2" : "=v"(wp[d2+0]) : "v"(p[o+0]), "v"(p[o+1]));
            asm("v_cvt_pk_bf16_f32 %0, %1, %2" : "=v"(wp[d2+1]) : "v"(p[o+2]), "v"(p[o+3]));
            asm("v_cvt_pk_bf16_f32 %0, %1, %2" : "=v"(wp[d2+2]) : "v"(p[o+4]), "v"(p[o+5]));
            asm("v_cvt_pk_bf16_f32 %0, %1, %2" : "=v"(wp[d2+3]) : "v"(p[o+6]), "v"(p[o+7]));
            asm("v_permlane32_swap_b32 %0, %1" : "+v"(wp[d2+0]), "+v"(wp[d2+2]));
            asm("v_permlane32_swap_b32 %0, %1" : "+v"(wp[d2+1]), "+v"(wp[d2+3]));
        }
        union { unsigned int u[4]; bf16x8 v; } pa0, pa1;
        pa0.u[0] = wp[0]; pa0.u[1] = wp[1]; pa0.u[2] = wp[2]; pa0.u[3] = wp[3];
        pa1.u[0] = wp[4]; pa1.u[1] = wp[5]; pa1.u[2] = wp[6]; pa1.u[3] = wp[7];
        // ---- PV: O^T += V^T x P^T ----
        __builtin_amdgcn_s_setprio(1);
#pragma unroll
        for (int ph = 0; ph < 2; ++ph) {
            const bf16x8 pv = ph ? pa1.v : pa0.v;
#pragma unroll
            for (int dt = 0; dt < 2; ++dt) {
                int d = dt * 32 + l31;
                int slot = ((ph * 2 + hs) ^ ((d >> 1) & 3)) & 3;
                bf16x8 vb = *reinterpret_cast<const bf16x8*>(VT + d * 64 + slot * 16);
                if (dt == 0) oacc0 = MFMA32(vb, pv, oacc0);
                else         oacc1 = MFMA32(vb, pv, oacc1);
            }
        }
        __builtin_amdgcn_s_setprio(0);
    };

    // ---- main loop: per half, qt+1 tiles of 32 rows, dbuf prefetch ----
    stage(0, half * 32);
    __syncthreads();                  // prologue stage drained
    for (int i = 0; i <= qt; ++i) {
        int k0 = (2 * i + half) * 32;
        if (i < qt) stage((i + 1) & 1, (2 * (i + 1) + half) * 32);  // prefetch
        if (k0 <= q_lo) compute(i & 1, k0);       // skip if above diagonal
        __syncthreads();              // drains prefetch; orders buffer reuse
    }

    // ---- merge the two K-halves in-LDS (pure sums, layouts match) ----
    if (half == 1) {
#pragma unroll
        for (int r = 0; r < 16; ++r) {
            MRG[(wq * 32 + r) * 64 + lane]      = oacc0[r];
            MRG[(wq * 32 + 16 + r) * 64 + lane] = oacc1[r];
        }
        if (hs == 0) ML[wq * 32 + l31] = lsum;
    }
    __syncthreads();
    float inv = 0.f;
    if (half == 0) {
        lsum += ML[wq * 32 + l31];
        inv = 1.f / lsum;
#pragma unroll
        for (int r = 0; r < 16; ++r) {
            oacc0[r] += MRG[(wq * 32 + r) * 64 + lane];
            oacc1[r] += MRG[(wq * 32 + 16 + r) * 64 + lane];
        }
    }
    __syncthreads();                  // merge reads done before OT overwrite

    // ---- epilogue: normalize, stage OT[d][q], store attT bf16 ----
    if (half == 0) {
#pragma unroll
        for (int r = 0; r < 16; ++r) {
            int rowp = (r & 3) + 8 * (r >> 2) + 4 * hs;   // d-row within 32
            OT[(rowp)      * 68 + wq * 32 + l31] = oacc0[r] * inv;
            OT[(32 + rowp) * 68 + wq * 32 + l31] = oacc1[r] * inv;
        }
    }
    __syncthreads();
    {
        int d = tid >> 2, qb = tid & 3;   // 64 d x 4 groups of 16 q
        unsigned short tmp[16];
#pragma unroll
        for (int i = 0; i < 4; ++i) {
            f32x4 v = *reinterpret_cast<const f32x4*>(&OT[d * 68 + qb * 16 + i * 4]);
            tmp[i*4+0] = f2bf(v[0]); tmp[i*4+1] = f2bf(v[1]);
            tmp[i*4+2] = f2bf(v[2]); tmp[i*4+3] = f2bf(v[3]);
        }
        unsigned short* dst = attT + ((size_t)bh * 64 + d) * T_DIM + qt * 64 + qb * 16;
        *reinterpret_cast<u16x8*>(dst)     = *reinterpret_cast<u16x8*>(&tmp[0]);
        *reinterpret_cast<u16x8*>(dst + 8) = *reinterpret_cast<u16x8*>(&tmp[8]);
    }
}

// ---------------- Kernel 3: out = attT(as [4096][1024]) @ Wr^T + br ----------
__global__ __launch_bounds__(256) void final_gemm_mfma(
    const unsigned short* __restrict__ A, const unsigned short* __restrict__ Bw,
    const float* __restrict__ br, float* __restrict__ out)
{
    __shared__ __align__(16) unsigned char gsm[49152];   // 2 x (A 16KB + B 8KB)
    int nt = blockIdx.x;
    int mt = blockIdx.y;
    int tid = threadIdx.x;
    int w = tid >> 6;
    int lane = tid & 63;
    int l31 = lane & 31, hs = lane >> 5;
    int srow = lane >> 3, scol = lane & 7;
    int lsw = (l31 & 7) ^ (((l31 >> 3) & 3) << 1);

    auto stage = [&](int bs, int kt) {
        unsigned char* As = gsm + bs * 24576;
        unsigned char* Bs = As + 16384;
#pragma unroll
        for (int i = 0; i < 4; ++i) {
            int row = i * 32 + w * 8 + srow;
            int cd = scol ^ srow ^ (((row >> 3) & 3) << 1);
            gload16(A + (size_t)(mt * 128 + row) * 1024 + kt * 64 + cd * 8,
                    As + i * 4096 + w * 1024 + lane * 16);
        }
#pragma unroll
        for (int i = 0; i < 2; ++i) {
            int row = i * 32 + w * 8 + srow;
            int cd = scol ^ srow ^ (((row >> 3) & 3) << 1);
            gload16(Bw + (size_t)(nt * 64 + row) * 1024 + kt * 64 + cd * 8,
                    Bs + i * 4096 + w * 1024 + lane * 16);
        }
    };

    f32x16 oa0 = zero16(), oa1 = zero16();
    stage(0, 0);
    __syncthreads();
    for (int kt = 0; kt < 16; ++kt) {
        if (kt < 15) stage((kt + 1) & 1, kt + 1);
        const unsigned char* As = gsm + (kt & 1) * 24576;
        const unsigned char* Bs = As + 16384;
        int arow = w * 32 + l31;
        int asw = (arow & 7) ^ (((arow >> 3) & 3) << 1);
        __builtin_amdgcn_s_setprio(1);
#pragma unroll
        for (int st = 0; st < 4; ++st) {
            int c = st * 2 + hs;
            bf16x8 af = *reinterpret_cast<const bf16x8*>(As + arow * 128 + ((c ^ asw) * 16));
            {
                bf16x8 bf0 = *reinterpret_cast<const bf16x8*>(Bs + l31 * 128 + ((c ^ lsw) * 16));
                oa0 = MFMA32(af, bf0, oa0);
            }
            {
                int brow = 32 + l31;
                bf16x8 bf1 = *reinterpret_cast<const bf16x8*>(Bs + brow * 128 + ((c ^ lsw) * 16));
                oa1 = MFMA32(af, bf1, oa1);
            }
        }
        __builtin_amdgcn_s_setprio(0);
        __syncthreads();
    }

#pragma unroll
    for (int ng = 0; ng < 2; ++ng) {
        int col = nt * 64 + ng * 32 + l31;
        float bias = br[col];
        const f32x16& oa = ng ? oa1 : oa0;
#pragma unroll
        for (int r = 0; r < 16; ++r) {
            int rowp = (r & 3) + 8 * (r >> 2) + 4 * hs;
            int row = mt * 128 + w * 32 + rowp;
            out[(size_t)row * 1024 + col] = oa[r] + bias;
        }
    }
}

extern "C" void kernel_launch(void* const* d_in, const int* in_sizes, int n_in,
                              void* d_out, int out_size, void* d_ws, size_t ws_size,
                              hipStream_t stream) {
    const float* x  = (const float*)d_in[0];
    const float* Wq = (const float*)d_in[1];
    const float* Wk = (const float*)d_in[2];
    const float* Wv = (const float*)d_in[3];
    const float* Er = (const float*)d_in[4];
    const float* Wr = (const float*)d_in[5];
    const float* br = (const float*)d_in[6];
    float* out = (float*)d_out;

    const size_t nQ = (size_t)B_DIM * H_DIM * T_DIM * S_DIM;   // 4,194,304
    char* p = (char*)d_ws;
    unsigned short* qb = (unsigned short*)p;   p += nQ * 2;
    unsigned short* kh = (unsigned short*)p;   p += nQ * 2;
    unsigned short* vT = (unsigned short*)p;   p += nQ * 2;
    unsigned short* attT = (unsigned short*)p; p += nQ * 2;
    unsigned short* wrb = (unsigned short*)p;  p += (size_t)E_DIM * E_DIM * 2;
    unsigned short* whb = (unsigned short*)p;  p += (size_t)3 * 65536 * 2;
    size_t need = (size_t)(p - (char*)d_ws);
    if (ws_size < need) {
        fprintf(stderr, "WS TOO SMALL: have %zu need %zu\n", ws_size, need);
        return;
    }

    prep_w<<<1216, 256, 0, stream>>>(Wq, Wk, Wv, Wr, whb, wrb);
    qkv_mfma<<<2048, 64, 0, stream>>>(x, whb, Er, qb, kh, vT);
    attn_mfma32<<<1024, 256, 0, stream>>>(qb, kh, vT, attT);
    final_gemm_mfma<<<dim3(16, 32), 256, 0, stream>>>(attT, wrb, br, out);
}

// Round 17
// 72.012 us; speedup vs baseline: 1.6188x; 1.0022x over previous
//
#include <hip/hip_runtime.h>
#include <hip/hip_bf16.h>
#include <cstdio>

#define T_DIM 2048
#define B_DIM 2
#define E_DIM 1024
#define H_DIM 16
#define S_DIM 64
#define LOG2E 1.44269504088896340736f

typedef __attribute__((ext_vector_type(4))) float f32x4;
typedef __attribute__((ext_vector_type(16))) float f32x16;
typedef __attribute__((ext_vector_type(8))) short bf16x8;
typedef __attribute__((ext_vector_type(8))) unsigned short u16x8;
typedef __attribute__((ext_vector_type(4))) unsigned short u16x4;

#define MFMA32(a,b,c) __builtin_amdgcn_mfma_f32_32x32x16_bf16((a),(b),(c),0,0,0)

__device__ __forceinline__ unsigned short f2bf(float f) {
    union { __hip_bfloat16 h; unsigned short u; } c;
    c.h = __float2bfloat16(f);
    return c.u;
}
__device__ __forceinline__ void gload16(const void* g, void* l) {
    __builtin_amdgcn_global_load_lds(
        (const __attribute__((address_space(1))) unsigned int*)g,
        (__attribute__((address_space(3))) unsigned int*)l, 16, 0, 0);
}
__device__ __forceinline__ f32x16 zero16() {
    f32x16 v;
#pragma unroll
    for (int i = 0; i < 16; ++i) v[i] = 0.f;
    return v;
}

// ---------------- Kernel 0: weight prep (all weights -> bf16) ----------------
__global__ __launch_bounds__(256) void prep_w(
    const float* __restrict__ Wq, const float* __restrict__ Wk,
    const float* __restrict__ Wv, const float* __restrict__ Wr,
    unsigned short* __restrict__ whb, unsigned short* __restrict__ wrb)
{
    int bid = blockIdx.x;
    if (bid < 192) {
        int i = bid * 256 + threadIdx.x;   // float4 idx < 49152
        const float* src = (i < 16384) ? Wq : ((i < 32768) ? Wk : Wv);
        float4 v = reinterpret_cast<const float4*>(src)[i & 16383];
        u16x4 o;
        o[0] = f2bf(v.x); o[1] = f2bf(v.y); o[2] = f2bf(v.z); o[3] = f2bf(v.w);
        *reinterpret_cast<u16x4*>(whb + (size_t)i * 4) = o;
    } else {
        int i = (bid - 192) * 256 + threadIdx.x;   // float4 idx < 262144
        float4 v = reinterpret_cast<const float4*>(Wr)[i];
        u16x4 o;
        o[0] = f2bf(v.x); o[1] = f2bf(v.y); o[2] = f2bf(v.z); o[3] = f2bf(v.w);
        *reinterpret_cast<u16x4*>(wrb + (size_t)i * 4) = o;
    }
}

// ---------------- Kernel 1: QKV projection, plain bf16 MFMA ----------------
// One wave per block, dg-loop: both 32-d halves done by the same block so the
// x tile is loaded/converted once.
__global__ __launch_bounds__(64) void qkv_mfma(
    const float* __restrict__ x, const unsigned short* __restrict__ wb,
    const float* __restrict__ Er,
    unsigned short* __restrict__ qb_g, unsigned short* __restrict__ kh_g,
    unsigned short* __restrict__ vT_g)
{
    int bid = blockIdx.x;
    int tt = bid & 63;
    int h  = (bid >> 6) & 15;
    int b  = bid >> 10;
    int bh = b * H_DIM + h;
    int t0 = tt * 32;
    int lane = threadIdx.x;
    int l31 = lane & 31, hs = lane >> 5;

    bf16x8 xb[4];
    const float* xrow = x + (size_t)(t0 + l31) * (B_DIM * E_DIM) + (size_t)b * E_DIM + h * 64;
#pragma unroll
    for (int ks = 0; ks < 4; ++ks) {
        float vv[8];
        *reinterpret_cast<float4*>(&vv[0]) = *reinterpret_cast<const float4*>(xrow + ks * 16 + hs * 8);
        *reinterpret_cast<float4*>(&vv[4]) = *reinterpret_cast<const float4*>(xrow + ks * 16 + hs * 8 + 4);
        unsigned short hh[8];
#pragma unroll
        for (int j = 0; j < 8; ++j) hh[j] = f2bf(vv[j]);
        xb[ks] = *reinterpret_cast<bf16x8*>(hh);
    }

    size_t rowbase = (size_t)bh * T_DIM * 64;
#pragma unroll 1
    for (int dg = 0; dg < 2; ++dg) {
        f32x16 aq = zero16(), ak = zero16(), av = zero16();
        size_t wofs = (size_t)h * 4096 + (size_t)(dg * 32 + l31) * 64 + hs * 8;
#pragma unroll
        for (int ks = 0; ks < 4; ++ks) {
            bf16x8 qw = *reinterpret_cast<const bf16x8*>(wb + wofs + ks * 16);
            bf16x8 kw = *reinterpret_cast<const bf16x8*>(wb + 65536 + wofs + ks * 16);
            bf16x8 vw = *reinterpret_cast<const bf16x8*>(wb + 131072 + wofs + ks * 16);
            aq = MFMA32(xb[ks], qw, aq);
            ak = MFMA32(xb[ks], kw, ak);
            av = MFMA32(vw, xb[ks], av);   // v computed transposed: D = W*x^T
        }
#pragma unroll
        for (int r = 0; r < 16; ++r) {
            int rowp = (r & 3) + 8 * (r >> 2) + 4 * hs;
            int t = t0 + rowp;
            int d = dg * 32 + l31;
            size_t ro = rowbase + (size_t)t * 64 + d;
            qb_g[ro] = f2bf(aq[r]);
            float kv = (ak[r] * 0.03125f + Er[(size_t)d * T_DIM + t]) * LOG2E;
            kh_g[ro] = f2bf(kv);
            vT_g[((size_t)bh * 64 + dg * 32 + rowp) * T_DIM + t0 + l31] = f2bf(av[r]);
        }
    }
}

// ---------------- Kernel 2: causal flash attention ---------------------------
// 1024 blocks x 4 waves (256 thr): block = 64 q-rows (2 wq x 32q), 2-way
// K-split over 32-row K-tiles. DOUBLE-BUFFERED prefetch-before-compute in
// 32768 B exactly (per half: 2 bufs x (K 4KB + V 4KB)) -> 5 blocks/CU AND
// stage(i+1) hides under compute(i) (the r12-r15 single-buffer structure
// fully exposed stage latency: barrier-stage-barrier-compute).
// Bounds stay (256,4): declaring 5 waves/EU capped VGPR->48 and spilled (R14).
// No-max softmax; in-LDS half merge; static quad-balanced qt map.
__global__ __launch_bounds__(256, 4) void attn_mfma32(
    const unsigned short* __restrict__ qb_g, const unsigned short* __restrict__ kh_g,
    const unsigned short* __restrict__ vT_g, unsigned short* __restrict__ attT)
{
    __shared__ __align__(16) unsigned char smem[32768];
    float* OT  = (float*)smem;            // [64][68] f32 epilogue (aliases KV)
    float* MRG = (float*)smem;            // [64][64] f32 = 16KB merge (aliases KV)
    float* ML  = (float*)(smem + 16384);  // [64] f32 (aliases half-1 bufs; safe:
                                          // used only after final compute barrier)

    int bid = blockIdx.x;
    int bh = bid & 31;            // bh%8 = XCD -> 4 heads/XCD, K/V L2-resident
    int u = bid >> 5;             // 0..31
    int j = u & 7, quad = u >> 3;
    int qt = (quad == 0) ? (31 - j) : (quad == 1) ? j
           : (quad == 2) ? (23 - j) : (8 + j);

    int tid = threadIdx.x;
    int w = tid >> 6;             // 0..3
    int half = w >> 1;            // K-split half (32-row tiles, parity = half)
    int wq = w & 1;               // q sub-block
    int lane = tid & 63;
    int l31 = lane & 31, hs = lane >> 5;
    int srow = lane >> 3, scol = lane & 7;       // K staging split
    int vrow = lane >> 2, vcol = lane & 3;       // V staging split
    int lsw = (l31 & 7) ^ (((l31 >> 3) & 3) << 1);   // K read-side row swizzle
    int q_lo = qt * 64 + wq * 32;
    size_t base = (size_t)bh * T_DIM * 64;

    // Q fragments (held in registers)
    bf16x8 qB[4];
    {
        size_t qoff = base + (size_t)(q_lo + l31) * 64 + hs * 8;
#pragma unroll
        for (int st = 0; st < 4; ++st)
            qB[st] = *reinterpret_cast<const bf16x8*>(qb_g + qoff + st * 16);
    }

    f32x16 oacc0 = zero16(), oacc1 = zero16();   // O^T: col=q(lane), regs=d
    float lsum = 0.f;

    unsigned char* hbase = smem + half * 16384;  // this half's 2 buffers

    // stage one 32-row K-tile (4KB) + V^T slice (4KB) into buffer bs
    auto stage = [&](int bs, int k0) {
        unsigned char* KH = hbase + bs * 8192;
        unsigned char* VT = KH + 4096;
#pragma unroll
        for (int ci = 0; ci < 2; ++ci) {          // K: 32 rows x 128 B
            int row = ci * 16 + wq * 8 + srow;
            int swz = (row & 7) ^ (((row >> 3) & 3) << 1);
            gload16(kh_g + base + (size_t)(k0 + row) * 64 + (scol ^ swz) * 8,
                    KH + ci * 2048 + wq * 1024 + lane * 16);
        }
#pragma unroll
        for (int ci = 0; ci < 2; ++ci) {          // V: 64 d-rows x 64 B
            int d = ci * 32 + wq * 16 + vrow;
            int swz = (d >> 1) & 3;
            gload16(vT_g + base + (size_t)d * T_DIM + k0 + ((vcol ^ swz) & 3) * 8,
                    VT + ci * 2048 + wq * 1024 + lane * 16);
        }
    };

    // compute one 32-row subtile from buffer bs
    auto compute = [&](int bs, int k0) {
        const unsigned char* KH = hbase + bs * 8192;
        const unsigned char* VT = KH + 4096;
        // ---- S^T = K' x Q: col=q=l31, regs=krow ----
        f32x16 s = zero16();
        __builtin_amdgcn_s_setprio(1);
#pragma unroll
        for (int st = 0; st < 4; ++st) {
            int slot = (st * 2 + hs) ^ lsw;
            bf16x8 kf = *reinterpret_cast<const bf16x8*>(KH + l31 * 128 + slot * 16);
            s = MFMA32(kf, qB[st], s);
        }
        __builtin_amdgcn_s_setprio(0);
        if (k0 == q_lo) {                         // diagonal subtile mask
#pragma unroll
            for (int r = 0; r < 16; ++r) {
                int rowp = (r & 3) + 8 * (r >> 2) + 4 * hs;
                if (rowp > l31) s[r] = -1e30f;
            }
        }
        // ---- no-max softmax (log2-scores fit fp32 exp2 range) ----
        float p[16], psum = 0.f;
#pragma unroll
        for (int r = 0; r < 16; ++r) {
            p[r] = __builtin_amdgcn_exp2f(s[r]);
            psum += p[r];
        }
        lsum += psum + __shfl_xor(psum, 32);
        // ---- P -> bf16 in-register (cvt_pk + permlane32_swap) ----
        unsigned int wp[8];
#pragma unroll
        for (int q2 = 0; q2 < 2; ++q2) {
            int o = q2 * 8, d2 = q2 * 4;
            asm("v_cvt_pk_bf16_f32 %0, %1, %2" : "=v"(wp[d2+0]) : "v"(p[o+0]), "v"(p[o+1]));
            asm("v_cvt_pk_bf16_f32 %0, %1, %2" : "=v"(wp[d2+1]) : "v"(p[o+2]), "v"(p[o+3]));
            asm("v_cvt_pk_bf16_f32 %0, %1, %2" : "=v"(wp[d2+2]) : "v"(p[o+4]), "v"(p[o+5]));
            asm("v_cvt_pk_bf16_f32 %0, %1, %2" : "=v"(wp[d2+3]) : "v"(p[o+6]), "v"(p[o+7]));
            asm("v_permlane32_swap_b32 %0, %1" : "+v"(wp[d2+0]), "+v"(wp[d2+2]));
            asm("v_permlane32_swap_b32 %0, %1" : "+v"(wp[d2+1]), "+v"(wp[d2+3]));
        }
        union { unsigned int u[4]; bf16x8 v; } pa0, pa1;
        pa0.u[0] = wp[0]; pa0.u[1] = wp[1]; pa0.u[2] = wp[2]; pa0.u[3] = wp[3];
        pa1.u[0] = wp[4]; pa1.u[1] = wp[5]; pa1.u[2] = wp[6]; pa1.u[3] = wp[7];
        // ---- PV: O^T += V^T x P^T ----
        __builtin_amdgcn_s_setprio(1);
#pragma unroll
        for (int ph = 0; ph < 2; ++ph) {
            const bf16x8 pv = ph ? pa1.v : pa0.v;
#pragma unroll
            for (int dt = 0; dt < 2; ++dt) {
                int d = dt * 32 + l31;
                int slot = ((ph * 2 + hs) ^ ((d >> 1) & 3)) & 3;
                bf16x8 vb = *reinterpret_cast<const bf16x8*>(VT + d * 64 + slot * 16);
                if (dt == 0) oacc0 = MFMA32(vb, pv, oacc0);
                else         oacc1 = MFMA32(vb, pv, oacc1);
            }
        }
        __builtin_amdgcn_s_setprio(0);
    };

    // ---- main loop: per half, qt+1 tiles of 32 rows, dbuf prefetch ----
    stage(0, half * 32);
    __syncthreads();                  // prologue stage drained
    for (int i = 0; i <= qt; ++i) {
        int k0 = (2 * i + half) * 32;
        if (i < qt) stage((i + 1) & 1, (2 * (i + 1) + half) * 32);  // prefetch
        if (k0 <= q_lo) compute(i & 1, k0);       // skip if above diagonal
        __syncthreads();              // drains prefetch; orders buffer reuse
    }

    // ---- merge the two K-halves in-LDS (pure sums, layouts match) ----
    if (half == 1) {
#pragma unroll
        for (int r = 0; r < 16; ++r) {
            MRG[(wq * 32 + r) * 64 + lane]      = oacc0[r];
            MRG[(wq * 32 + 16 + r) * 64 + lane] = oacc1[r];
        }
        if (hs == 0) ML[wq * 32 + l31] = lsum;
    }
    __syncthreads();
    float inv = 0.f;
    if (half == 0) {
        lsum += ML[wq * 32 + l31];
        inv = 1.f / lsum;
#pragma unroll
        for (int r = 0; r < 16; ++r) {
            oacc0[r] += MRG[(wq * 32 + r) * 64 + lane];
            oacc1[r] += MRG[(wq * 32 + 16 + r) * 64 + lane];
        }
    }
    __syncthreads();                  // merge reads done before OT overwrite

    // ---- epilogue: normalize, stage OT[d][q], store attT bf16 ----
    if (half == 0) {
#pragma unroll
        for (int r = 0; r < 16; ++r) {
            int rowp = (r & 3) + 8 * (r >> 2) + 4 * hs;   // d-row within 32
            OT[(rowp)      * 68 + wq * 32 + l31] = oacc0[r] * inv;
            OT[(32 + rowp) * 68 + wq * 32 + l31] = oacc1[r] * inv;
        }
    }
    __syncthreads();
    {
        int d = tid >> 2, qb = tid & 3;   // 64 d x 4 groups of 16 q
        unsigned short tmp[16];
#pragma unroll
        for (int i = 0; i < 4; ++i) {
            f32x4 v = *reinterpret_cast<const f32x4*>(&OT[d * 68 + qb * 16 + i * 4]);
            tmp[i*4+0] = f2bf(v[0]); tmp[i*4+1] = f2bf(v[1]);
            tmp[i*4+2] = f2bf(v[2]); tmp[i*4+3] = f2bf(v[3]);
        }
        unsigned short* dst = attT + ((size_t)bh * 64 + d) * T_DIM + qt * 64 + qb * 16;
        *reinterpret_cast<u16x8*>(dst)     = *reinterpret_cast<u16x8*>(&tmp[0]);
        *reinterpret_cast<u16x8*>(dst + 8) = *reinterpret_cast<u16x8*>(&tmp[8]);
    }
}

// ---------------- Kernel 3: out = attT(as [4096][1024]) @ Wr^T + br ----------
__global__ __launch_bounds__(256) void final_gemm_mfma(
    const unsigned short* __restrict__ A, const unsigned short* __restrict__ Bw,
    const float* __restrict__ br, float* __restrict__ out)
{
    __shared__ __align__(16) unsigned char gsm[49152];   // 2 x (A 16KB + B 8KB)
    int nt = blockIdx.x;
    int mt = blockIdx.y;
    int tid = threadIdx.x;
    int w = tid >> 6;
    int lane = tid & 63;
    int l31 = lane & 31, hs = lane >> 5;
    int srow = lane >> 3, scol = lane & 7;
    int lsw = (l31 & 7) ^ (((l31 >> 3) & 3) << 1);

    auto stage = [&](int bs, int kt) {
        unsigned char* As = gsm + bs * 24576;
        unsigned char* Bs = As + 16384;
#pragma unroll
        for (int i = 0; i < 4; ++i) {
            int row = i * 32 + w * 8 + srow;
            int cd = scol ^ srow ^ (((row >> 3) & 3) << 1);
            gload16(A + (size_t)(mt * 128 + row) * 1024 + kt * 64 + cd * 8,
                    As + i * 4096 + w * 1024 + lane * 16);
        }
#pragma unroll
        for (int i = 0; i < 2; ++i) {
            int row = i * 32 + w * 8 + srow;
            int cd = scol ^ srow ^ (((row >> 3) & 3) << 1);
            gload16(Bw + (size_t)(nt * 64 + row) * 1024 + kt * 64 + cd * 8,
                    Bs + i * 4096 + w * 1024 + lane * 16);
        }
    };

    f32x16 oa0 = zero16(), oa1 = zero16();
    stage(0, 0);
    __syncthreads();
    for (int kt = 0; kt < 16; ++kt) {
        if (kt < 15) stage((kt + 1) & 1, kt + 1);
        const unsigned char* As = gsm + (kt & 1) * 24576;
        const unsigned char* Bs = As + 16384;
        int arow = w * 32 + l31;
        int asw = (arow & 7) ^ (((arow >> 3) & 3) << 1);
        __builtin_amdgcn_s_setprio(1);
#pragma unroll
        for (int st = 0; st < 4; ++st) {
            int c = st * 2 + hs;
            bf16x8 af = *reinterpret_cast<const bf16x8*>(As + arow * 128 + ((c ^ asw) * 16));
            {
                bf16x8 bf0 = *reinterpret_cast<const bf16x8*>(Bs + l31 * 128 + ((c ^ lsw) * 16));
                oa0 = MFMA32(af, bf0, oa0);
            }
            {
                int brow = 32 + l31;
                bf16x8 bf1 = *reinterpret_cast<const bf16x8*>(Bs + brow * 128 + ((c ^ lsw) * 16));
                oa1 = MFMA32(af, bf1, oa1);
            }
        }
        __builtin_amdgcn_s_setprio(0);
        __syncthreads();
    }

#pragma unroll
    for (int ng = 0; ng < 2; ++ng) {
        int col = nt * 64 + ng * 32 + l31;
        float bias = br[col];
        const f32x16& oa = ng ? oa1 : oa0;
#pragma unroll
        for (int r = 0; r < 16; ++r) {
            int rowp = (r & 3) + 8 * (r >> 2) + 4 * hs;
            int row = mt * 128 + w * 32 + rowp;
            out[(size_t)row * 1024 + col] = oa[r] + bias;
        }
    }
}

extern "C" void kernel_launch(void* const* d_in, const int* in_sizes, int n_in,
                              void* d_out, int out_size, void* d_ws, size_t ws_size,
                              hipStream_t stream) {
    const float* x  = (const float*)d_in[0];
    const float* Wq = (const float*)d_in[1];
    const float* Wk = (const float*)d_in[2];
    const float* Wv = (const float*)d_in[3];
    const float* Er = (const float*)d_in[4];
    const float* Wr = (const float*)d_in[5];
    const float* br = (const float*)d_in[6];
    float* out = (float*)d_out;

    const size_t nQ = (size_t)B_DIM * H_DIM * T_DIM * S_DIM;   // 4,194,304
    char* p = (char*)d_ws;
    unsigned short* qb = (unsigned short*)p;   p += nQ * 2;
    unsigned short* kh = (unsigned short*)p;   p += nQ * 2;
    unsigned short* vT = (unsigned short*)p;   p += nQ * 2;
    unsigned short* attT = (unsigned short*)p; p += nQ * 2;
    unsigned short* wrb = (unsigned short*)p;  p += (size_t)E_DIM * E_DIM * 2;
    unsigned short* whb = (unsigned short*)p;  p += (size_t)3 * 65536 * 2;
    size_t need = (size_t)(p - (char*)d_ws);
    if (ws_size < need) {
        fprintf(stderr, "WS TOO SMALL: have %zu need %zu\n", ws_size, need);
        return;
    }

    prep_w<<<1216, 256, 0, stream>>>(Wq, Wk, Wv, Wr, whb, wrb);
    qkv_mfma<<<2048, 64, 0, stream>>>(x, whb, Er, qb, kh, vT);
    attn_mfma32<<<1024, 256, 0, stream>>>(qb, kh, vT, attT);
    final_gemm_mfma<<<dim3(16, 32), 256, 0, stream>>>(attT, wrb, br, out);
}